// Round 12
// baseline (192.562 us; speedup 1.0000x reference)
//
#include <hip/hip_runtime.h>
#include <math.h>

#define CDIM 128
#define HEADS 4
#define NEG 0.2f
#define NSHARD 4

typedef __attribute__((ext_vector_type(8))) short bf16x8;
typedef __attribute__((ext_vector_type(8))) unsigned short u16x8;
typedef __attribute__((ext_vector_type(4))) float f32x4;

static __device__ __forceinline__ unsigned short f2bf(float f) {
    unsigned u = __float_as_uint(f);
    u += 0x7FFFu + ((u >> 16) & 1u);   // round-to-nearest-even
    return (unsigned short)(u >> 16);
}
static __device__ __forceinline__ float bf2f(unsigned short s) {
    return __uint_as_float((unsigned)s << 16);
}

#define LDS_STRIDE 136   // 128 + 8 bf16 pad

// ---------------- tiny precursor: WT[c][k] = bf16(W[k][c]), 32 KB global ----------------
__global__ __launch_bounds__(256) void wt_kernel(const float* __restrict__ W,
                                                 unsigned short* __restrict__ WT) {
    int f = blockIdx.x * 256 + threadIdx.x;       // 4096 total
    int k = f >> 5, c4 = (f & 31) * 4;
    float4 v = *(const float4*)(W + (size_t)k * CDIM + c4);
    WT[(size_t)(c4 + 0) * CDIM + k] = f2bf(v.x);
    WT[(size_t)(c4 + 1) * CDIM + k] = f2bf(v.y);
    WT[(size_t)(c4 + 2) * CDIM + k] = f2bf(v.z);
    WT[(size_t)(c4 + 3) * CDIM + k] = f2bf(v.w);
}

// ---------------- fused: MFMA GEMM (+logits, bf16 out)  ∥  sharded edge histogram ----------------
__global__ __launch_bounds__(256) void gemm_hist_kernel(const float* __restrict__ x,
                                                        const unsigned short* __restrict__ WT,
                                                        const float* __restrict__ att_src,
                                                        const float* __restrict__ att_dst,
                                                        unsigned short* __restrict__ xlh,
                                                        float* __restrict__ a_src,
                                                        float* __restrict__ a_dst, int N,
                                                        const int* __restrict__ esrc,
                                                        const int* __restrict__ edst,
                                                        int* __restrict__ counts_sh,  // [NSHARD][N]
                                                        int* __restrict__ rank, int E,
                                                        int gemmBlocks) {
    __shared__ unsigned short As[64 * LDS_STRIDE];   // 17.4 KB only

    if (blockIdx.x >= gemmBlocks) {
        // ---- sharded histogram branch: shard by (e & 3) cuts same-address chains 4x ----
        int e = (blockIdx.x - gemmBlocks) * 256 + threadIdx.x;
        if (e < E) {
            int s = esrc[e], d = edst[e];
            if (s != d) {
                int sh = e & (NSHARD - 1);
                rank[e] = atomicAdd(&counts_sh[(size_t)sh * N + d], 1);
            }
        }
        return;
    }

    // ---- gemm branch ----
    const int tid = threadIdx.x;
    const int row0 = blockIdx.x * 64;

#pragma unroll
    for (int i = 0; i < 8; ++i) {
        int f = tid + i * 256;
        int r = f >> 5, k4 = f & 31;
        float4 v = make_float4(0.f, 0.f, 0.f, 0.f);
        int gr = row0 + r;
        if (gr < N) v = *(const float4*)(x + (size_t)gr * CDIM + k4 * 4);
        ushort4 h;
        h.x = f2bf(v.x); h.y = f2bf(v.y); h.z = f2bf(v.z); h.w = f2bf(v.w);
        *(ushort4*)(&As[r * LDS_STRIDE + k4 * 4]) = h;
    }
    __syncthreads();

    const int wave = tid >> 6;
    const int lane = tid & 63;
    const int m    = lane & 15;
    const int quad = lane >> 4;
    const int wrow = wave * 16;

    bf16x8 a[4];
#pragma unroll
    for (int ks = 0; ks < 4; ++ks)
        a[ks] = *(const bf16x8*)(&As[(wrow + m) * LDS_STRIDE + ks * 32 + quad * 8]);

    f32x4 acc[8];
#pragma unroll
    for (int t = 0; t < 8; ++t) {
        f32x4 c = {0.f, 0.f, 0.f, 0.f};
#pragma unroll
        for (int ks = 0; ks < 4; ++ks) {
            bf16x8 b = *(const bf16x8*)(WT + (size_t)(t * 16 + m) * CDIM + ks * 32 + quad * 8);
            c = __builtin_amdgcn_mfma_f32_16x16x32_bf16(a[ks], b, c, 0, 0, 0);
        }
        acc[t] = c;
    }

#pragma unroll
    for (int t = 0; t < 8; ++t) {
#pragma unroll
        for (int reg = 0; reg < 4; ++reg) {
            int row = row0 + wrow + quad * 4 + reg;
            if (row < N) xlh[(size_t)row * CDIM + t * 16 + m] = f2bf(acc[t][reg]);
        }
    }

    float ps[4][4], pd[4][4];
#pragma unroll
    for (int h = 0; h < 4; ++h)
#pragma unroll
        for (int reg = 0; reg < 4; ++reg) { ps[h][reg] = 0.f; pd[h][reg] = 0.f; }
#pragma unroll
    for (int t = 0; t < 8; ++t) {
        int h = t >> 1;
        float vs = att_src[t * 16 + m];
        float vd = att_dst[t * 16 + m];
#pragma unroll
        for (int reg = 0; reg < 4; ++reg) {
            ps[h][reg] += acc[t][reg] * vs;
            pd[h][reg] += acc[t][reg] * vd;
        }
    }
#pragma unroll
    for (int off = 8; off > 0; off >>= 1) {
#pragma unroll
        for (int h = 0; h < 4; ++h)
#pragma unroll
            for (int reg = 0; reg < 4; ++reg) {
                ps[h][reg] += __shfl_down(ps[h][reg], off, 16);
                pd[h][reg] += __shfl_down(pd[h][reg], off, 16);
            }
    }
    if (m == 0) {
#pragma unroll
        for (int reg = 0; reg < 4; ++reg) {
            int row = row0 + wrow + quad * 4 + reg;
            if (row < N) {
#pragma unroll
                for (int h = 0; h < 4; ++h) {
                    a_src[row * 4 + h] = ps[h][reg];
                    a_dst[row * 4 + h] = pd[h][reg];
                }
            }
        }
    }
}

// ---------------- scan: sum shard counts, block scan, atomic base; emit {beg,cnt} + shard bases ----------------
__global__ __launch_bounds__(256) void scan_fused_kernel(const int* __restrict__ counts_sh,
                                                         int2* __restrict__ ocnt,
                                                         int4* __restrict__ sbase,
                                                         int* __restrict__ cursor, int N) {
    __shared__ int sh[256];
    __shared__ int baseSh;
    int idx = blockIdx.x * 256 + threadIdx.x;
    int t = threadIdx.x;
    int c0 = 0, c1 = 0, c2 = 0, c3 = 0;
    if (idx < N) {
        c0 = counts_sh[idx];
        c1 = counts_sh[(size_t)N + idx];
        c2 = counts_sh[(size_t)2 * N + idx];
        c3 = counts_sh[(size_t)3 * N + idx];
    }
    int tot = c0 + c1 + c2 + c3;
    sh[t] = tot;
    __syncthreads();
    for (int off = 1; off < 256; off <<= 1) {
        int v = (t >= off) ? sh[t - off] : 0;
        __syncthreads();
        sh[t] += v;
        __syncthreads();
    }
    if (t == 255) baseSh = atomicAdd(cursor, sh[255]);
    __syncthreads();
    if (idx < N) {
        int beg = baseSh + sh[t] - tot;
        ocnt[idx] = make_int2(beg, tot);
        sbase[idx] = make_int4(beg, beg + c0, beg + c0 + c1, beg + c0 + c1 + c2);
    }
}

// pure scatter: slot = sbase[d][shard] + rank
__global__ __launch_bounds__(256) void scatter_kernel(const int* __restrict__ src,
                                                      const int* __restrict__ dst,
                                                      const int4* __restrict__ sbase,
                                                      const int* __restrict__ rank,
                                                      int* __restrict__ bucket, int E) {
    int e = blockIdx.x * 256 + threadIdx.x;
    if (e >= E) return;
    int s = src[e], d = dst[e];
    if (s == d) return;
    int4 sb = sbase[d];
    int base = ((const int*)&sb)[e & (NSHARD - 1)];
    bucket[base + rank[e]] = s;
}

// ---------------- gather: 16 lanes/node (ushort8), one node/group, 8x unrolled ----------------
__global__ __launch_bounds__(256) void gather_kernel(const int2* __restrict__ ocnt,
                                                     const int* __restrict__ bucket,
                                                     const unsigned short* __restrict__ xlh,
                                                     const float* __restrict__ a_src,
                                                     const float* __restrict__ a_dst,
                                                     const float* __restrict__ bias,
                                                     float* __restrict__ out, int N) {
    const int node = blockIdx.x * 16 + (threadIdx.x >> 4);
    const int lane16 = threadIdx.x & 15;
    if (node >= N) return;
    const int c8 = lane16 * 8;
    const int h = lane16 >> 2;

    const float ad = a_dst[node * 4 + h];
    int2 oc = ocnt[node];
    const int beg = oc.x;
    const int cnt = oc.y;

    float acc[8];
#pragma unroll
    for (int i = 0; i < 8; ++i) acc[i] = 0.f;
    float den = 0.f;

    int j = 0;
    for (; j + 8 <= cnt; j += 8) {
        int s[8];
#pragma unroll
        for (int q = 0; q < 8; ++q) s[q] = bucket[beg + j + q];
        float e[8];
#pragma unroll
        for (int q = 0; q < 8; ++q) e[q] = a_src[s[q] * 4 + h] + ad;
        u16x8 u[8];
#pragma unroll
        for (int q = 0; q < 8; ++q) u[q] = *(const u16x8*)(xlh + (size_t)s[q] * CDIM + c8);
        float w[8];
#pragma unroll
        for (int q = 0; q < 8; ++q) {
            float eq = e[q] > 0.f ? e[q] : NEG * e[q];
            w[q] = __expf(eq);
        }
#pragma unroll
        for (int q = 0; q < 8; ++q) {
#pragma unroll
            for (int i = 0; i < 8; ++i) acc[i] += w[q] * bf2f(u[q][i]);
            den += w[q];
        }
    }
    for (; j < cnt; ++j) {
        int s = bucket[beg + j];
        float e = a_src[s * 4 + h] + ad;
        u16x8 u = *(const u16x8*)(xlh + (size_t)s * CDIM + c8);
        e = e > 0.f ? e : NEG * e;
        float w = __expf(e);
#pragma unroll
        for (int i = 0; i < 8; ++i) acc[i] += w * bf2f(u[i]);
        den += w;
    }
    // self loop
    float es = a_src[node * 4 + h] + ad;
    es = es > 0.f ? es : NEG * es;
    float ws = __expf(es);
    u16x8 u = *(const u16x8*)(xlh + (size_t)node * CDIM + c8);
#pragma unroll
    for (int i = 0; i < 8; ++i) acc[i] += ws * bf2f(u[i]);
    den += ws;

    float inv = 1.0f / den;
    float4 b0 = *(const float4*)(bias + c8);
    float4 b1 = *(const float4*)(bias + c8 + 4);
    float4 o0, o1;
    o0.x = (acc[0] * inv + b0.x) * 0.5f;
    o0.y = (acc[1] * inv + b0.y) * 0.5f;
    o0.z = (acc[2] * inv + b0.z) * 0.5f;
    o0.w = (acc[3] * inv + b0.w) * 0.5f;
    o1.x = (acc[4] * inv + b1.x) * 0.5f;
    o1.y = (acc[5] * inv + b1.y) * 0.5f;
    o1.z = (acc[6] * inv + b1.z) * 0.5f;
    o1.w = (acc[7] * inv + b1.w) * 0.5f;
    *(float4*)(out + (size_t)node * CDIM + c8) = o0;
    *(float4*)(out + (size_t)node * CDIM + c8 + 4) = o1;
}

extern "C" void kernel_launch(void* const* d_in, const int* in_sizes, int n_in,
                              void* d_out, int out_size, void* d_ws, size_t ws_size,
                              hipStream_t stream) {
    const float* x       = (const float*)d_in[0];
    const int*   ei      = (const int*)d_in[1];
    const float* W       = (const float*)d_in[2];
    const float* att_src = (const float*)d_in[3];
    const float* att_dst = (const float*)d_in[4];
    const float* bias    = (const float*)d_in[5];
    float* out = (float*)d_out;

    const int N = in_sizes[0] / CDIM;
    const int E = in_sizes[1] / 2;
    const int nb = (N + 255) / 256;

    char* wsb = (char*)d_ws;
    unsigned short* xlh = (unsigned short*)wsb;         wsb += (size_t)N * CDIM * sizeof(unsigned short);
    unsigned short* WT  = (unsigned short*)wsb;         wsb += (size_t)CDIM * CDIM * sizeof(unsigned short);
    float* a_src = (float*)wsb;                         wsb += (size_t)N * HEADS * sizeof(float);
    float* a_dst = (float*)wsb;                         wsb += (size_t)N * HEADS * sizeof(float);
    int* counts_sh = (int*)wsb;                         wsb += (size_t)NSHARD * N * sizeof(int);
    int* cursor  = (int*)wsb;                           wsb += sizeof(int);   // contiguous with counts_sh: one memset
    int2* ocnt   = (int2*)wsb;                          wsb += (size_t)N * sizeof(int2);
    int4* sbase  = (int4*)wsb;                          wsb += (size_t)N * sizeof(int4);
    int* rank    = (int*)wsb;                           wsb += (size_t)E * sizeof(int);
    int* bucket  = (int*)wsb;                           wsb += (size_t)E * sizeof(int);

    hipMemsetAsync(counts_sh, 0, ((size_t)NSHARD * N + 1) * sizeof(int), stream);

    wt_kernel<<<16, 256, 0, stream>>>(W, WT);
    const int gemmBlocks = (N + 63) / 64;
    const int histBlocks = (E + 255) / 256;
    gemm_hist_kernel<<<gemmBlocks + histBlocks, 256, 0, stream>>>(
        x, WT, att_src, att_dst, xlh, a_src, a_dst, N, ei, ei + E, counts_sh, rank, E, gemmBlocks);
    scan_fused_kernel<<<nb, 256, 0, stream>>>(counts_sh, ocnt, sbase, cursor, N);
    scatter_kernel<<<(E + 255) / 256, 256, 0, stream>>>(ei, ei + E, sbase, rank, bucket, E);
    gather_kernel<<<(N + 15) / 16, 256, 0, stream>>>(ocnt, bucket, xlh, a_src, a_dst, bias, out, N);
}